// Round 12
// baseline (354.120 us; speedup 1.0000x reference)
//
#include <hip/hip_runtime.h>
#include <hip/hip_fp16.h>
#include <math.h>

#define ALPHA 0.1f
#define EPS 1e-6f
#define D 64
#define CH 8192      // edges per block in hist/scatter kernels
#define BUCK_SH 8    // 256 nodes per bucket (nbuck = ceil(n/256) must be <= 512)

// --- per-block coarse histograms of dst>>8 and src>>8 (LDS, no global atomics)
__global__ void hist_kernel(const int* __restrict__ src, const int* __restrict__ dst,
                            int* __restrict__ hist_d, int* __restrict__ hist_s,
                            int nbuck, int nblk, int E) {
    __shared__ int hd[512], hs[512];
    int t = threadIdx.x, b = blockIdx.x;
    for (int u = t; u < 512; u += 256) { hd[u] = 0; hs[u] = 0; }
    __syncthreads();
    int beg = b * CH, end = min(beg + CH, E);
    for (int e = beg + t; e < end; e += 256) {
        atomicAdd(&hd[dst[e] >> BUCK_SH], 1);
        atomicAdd(&hs[src[e] >> BUCK_SH], 1);
    }
    __syncthreads();
    for (int u = t; u < nbuck; u += 256) {
        hist_d[u * nblk + b] = hd[u];   // [bucket][block] layout
        hist_s[u * nblk + b] = hs[u];
    }
}

// --- stage 1: per-bucket totals (one block per bucket, coalesced row sum) ---
__global__ void bucket_total_kernel(const int* __restrict__ hist_d, const int* __restrict__ hist_s,
                                    int* __restrict__ tot_d, int* __restrict__ tot_s, int nblk) {
    __shared__ int rd[256], rs[256];
    int u = blockIdx.x, t = threadIdx.x;
    int sd = 0, ss = 0;
    for (int b = t; b < nblk; b += 256) {
        sd += hist_d[u * nblk + b];
        ss += hist_s[u * nblk + b];
    }
    rd[t] = sd; rs[t] = ss;
    __syncthreads();
    for (int off = 128; off; off >>= 1) {
        if (t < off) { rd[t] += rd[t + off]; rs[t] += rs[t + off]; }
        __syncthreads();
    }
    if (t == 0) { tot_d[u] = rd[0]; tot_s[u] = rs[0]; }
}

// --- stage 2: exclusive scan of bucket totals (single 512-thread block) -----
__global__ void base_scan_kernel(const int* __restrict__ tot_d, const int* __restrict__ tot_s,
                                 int* __restrict__ base_d, int* __restrict__ base_s, int nbuck) {
    __shared__ int a[512], b[512];
    int t = threadIdx.x;
    int vd = (t < nbuck) ? tot_d[t] : 0;
    int vs = (t < nbuck) ? tot_s[t] : 0;
    a[t] = vd; b[t] = vs;
    __syncthreads();
    for (int off = 1; off < 512; off <<= 1) {
        int av = (t >= off) ? a[t - off] : 0;
        int bv = (t >= off) ? b[t - off] : 0;
        __syncthreads();
        a[t] += av; b[t] += bv;
        __syncthreads();
    }
    if (t < nbuck) {
        base_d[t] = a[t] - vd;   // exclusive
        base_s[t] = b[t] - vs;
    }
}

// --- stage 3: per-bucket row scan + bucket base -> scatter bases ------------
__global__ void row_scan_kernel(const int* __restrict__ hist_d, const int* __restrict__ hist_s,
                                const int* __restrict__ base_d, const int* __restrict__ base_s,
                                int* __restrict__ sbase_d, int* __restrict__ sbase_s,
                                int nblk, int E, int m) {
    __shared__ int a[512], b[512];
    int u = blockIdx.x, t = threadIdx.x;
    int hd = (t < nblk) ? hist_d[u * nblk + t] : 0;
    int hs = (t < nblk) ? hist_s[u * nblk + t] : 0;
    a[t] = hd; b[t] = hs;
    __syncthreads();
    for (int off = 1; off < 512; off <<= 1) {
        int av = (t >= off) ? a[t - off] : 0;
        int bv = (t >= off) ? b[t - off] : 0;
        __syncthreads();
        a[t] += av; b[t] += bv;
        __syncthreads();
    }
    if (t < nblk) {
        sbase_d[u * nblk + t] = base_d[u] + a[t] - hd;
        sbase_s[u * nblk + t] = base_s[u] + b[t] - hs;
    }
    if (u == 0 && t == 0) { sbase_d[m] = E; sbase_s[m] = E; }
}

// --- scatter edges into bucket-grouped arrays (LDS counters) ----------------
// pairs packed: (dst & 255) << 24 | src   (requires n < 2^24)
__global__ void scatter_kernel(const int* __restrict__ src, const int* __restrict__ dst,
                               const int* __restrict__ sbase_d, const int* __restrict__ sbase_s,
                               unsigned* __restrict__ pairs, unsigned char* __restrict__ skeys,
                               int nbuck, int nblk, int E) {
    __shared__ int cd[512], cs[512];
    int t = threadIdx.x, b = blockIdx.x;
    for (int u = t; u < nbuck; u += 256) {
        cd[u] = sbase_d[u * nblk + b];
        cs[u] = sbase_s[u * nblk + b];
    }
    __syncthreads();
    int beg = b * CH, end = min(beg + CH, E);
    for (int e = beg + t; e < end; e += 256) {
        int dv = dst[e], sv = src[e];
        int pu = atomicAdd(&cd[dv >> BUCK_SH], 1);
        pairs[pu] = ((unsigned)(dv & 255) << 24) | (unsigned)sv;
        int su = atomicAdd(&cs[sv >> BUCK_SH], 1);
        skeys[su] = (unsigned char)(sv & 255);
    }
}

// --- per-bucket build: sn, dn, rowptr, csr sorted by (dst, src-range) -------
__global__ void build_kernel(const unsigned* __restrict__ pairs, const int* __restrict__ sbase_d,
                             const unsigned char* __restrict__ skeys, const int* __restrict__ sbase_s,
                             int* __restrict__ rowptr, int* __restrict__ csr,
                             float* __restrict__ dn, float* __restrict__ sn,
                             int nbuck, int nblk, int n, int E, int rsh) {
    __shared__ int lh[2048];     // key hist -> exclusive prefix (in place)
    __shared__ int cnt[2048];    // placement counters
    __shared__ int lhs[256];     // src out-degree
    __shared__ int tsum[256];    // scan partials
    int t = threadIdx.x, u = blockIdx.x;
    for (int i = t; i < 2048; i += 256) { lh[i] = 0; cnt[i] = 0; }
    lhs[t] = 0;
    __syncthreads();
    // src-side per-node out-degree
    int sb = sbase_s[u * nblk];
    int se = sbase_s[(u + 1) * nblk];
    for (int i = sb + t; i < se; i += 256) atomicAdd(&lhs[skeys[i]], 1);
    // dst-side per-key histogram
    int beg = sbase_d[u * nblk];
    int end = sbase_d[(u + 1) * nblk];
    for (int i = beg + t; i < end; i += 256) {
        unsigned pr = pairs[i];
        int key = (int)((pr >> 24) << 3) | (int)((pr & 0xFFFFFFu) >> rsh);
        atomicAdd(&lh[key], 1);
    }
    __syncthreads();
    // exclusive scan of lh[0..2047]: 8 serial per thread + Hillis-Steele
    int base = t * 8, run = 0;
    #pragma unroll
    for (int k = 0; k < 8; ++k) { int v = lh[base + k]; lh[base + k] = run; run += v; }
    tsum[t] = run;
    __syncthreads();
    for (int off = 1; off < 256; off <<= 1) {
        int v = (t >= off) ? tsum[t - off] : 0;
        __syncthreads();
        tsum[t] += v;
        __syncthreads();
    }
    int add = (t == 0) ? 0 : tsum[t - 1];
    #pragma unroll
    for (int k = 0; k < 8; ++k) lh[base + k] += add;
    __syncthreads();
    // rowptr, dn, sn (t = dst_lo8)
    int node = (u << BUCK_SH) + t;
    if (node < n) {
        int r0 = lh[t * 8];
        int r1 = (t == 255) ? (end - beg) : lh[(t + 1) * 8];
        rowptr[node] = beg + r0;
        dn[node] = rsqrtf(fmaxf((float)(r1 - r0), 1.0f));
        sn[node] = rsqrtf(fmaxf((float)lhs[t], 1.0f));
    }
    if (u == nbuck - 1 && t == 0) rowptr[n] = E;
    // placement
    for (int i = beg + t; i < end; i += 256) {
        unsigned pr = pairs[i];
        unsigned sv = pr & 0xFFFFFFu;
        int key = (int)((pr >> 24) << 3) | (int)(sv >> rsh);
        int p = atomicAdd(&cnt[key], 1);
        csr[beg + lh[key] + p] = (int)sv;
    }
}

// --- seed: scaled_h[row] = feat*sn[row] (f16), pn[row] = sn*||feat[row]|| ---
__global__ void prescale_kernel(const float* __restrict__ feat, const float* __restrict__ sn,
                                __half* __restrict__ outh, float* __restrict__ pn, int n) {
    int row  = blockIdx.x * (blockDim.x >> 6) + (threadIdx.x >> 6);
    int lane = threadIdx.x & 63;
    if (row >= n) return;
    float x = feat[(long)row * D + lane];
    float ss = x * x;
    #pragma unroll
    for (int off = 32; off; off >>= 1) ss += __shfl_xor(ss, off, 64);
    float s = sn[row];
    float v = x * s;
    float vp = __shfl_xor(v, 1, 64);
    if (!(lane & 1)) {
        *(__half2*)(outh + (long)row * D + lane) = __floats2half2_rn(v, vp);
    }
    if (lane == 0) pn[row] = s * sqrtf(ss);
}

// --- fused iteration: one wave per dst row ----------------------------------
// lane = (g,sub): g (0..7) = edge slot, sub (0..7) = 16B (8-half) column slice.
// Per-lane DIRECT index load (no ds_bpermute in the gather dependency chain):
// lane handles edges e = g, 8+g, 16+g, ... of its row; 8 subs share one idx
// dword (L1 broadcast), row's index lines are L1-resident.
template <int LAST>
__global__ __launch_bounds__(256, 8)
void iter_kernel(const __half* __restrict__ cur, const float* __restrict__ feat0,
                 const int* __restrict__ rowptr, const int* __restrict__ csr_src,
                 const float* __restrict__ pn, const float* __restrict__ dn,
                 const float* __restrict__ sn,
                 __half* __restrict__ nexth, float* __restrict__ npn,
                 float* __restrict__ out, int n) {
    int row  = blockIdx.x * (blockDim.x >> 6) + (threadIdx.x >> 6);
    int lane = threadIdx.x & 63;
    if (row >= n) return;
    int g = lane >> 3, sub = lane & 7;

    int beg = rowptr[row], end = rowptr[row + 1];
    int deg = end - beg;
    const int* idx = csr_src + beg;
    unsigned subOff = (unsigned)sub * 16u;

    __half2 hz = __float2half2_rn(0.f);
    __half2 hacc0 = hz, hacc1 = hz, hacc2 = hz, hacc3 = hz;
    for (int e0 = g; e0 < deg; e0 += 32) {
        #pragma unroll
        for (int k = 0; k < 4; ++k) {
            int e = e0 + k * 8;
            if (e < deg) {
                int s = idx[e];
                int4 raw = *(const int4*)((const char*)cur + (unsigned)s * 128u + subOff);
                hacc0 = __hadd2(hacc0, *(const __half2*)&raw.x);
                hacc1 = __hadd2(hacc1, *(const __half2*)&raw.y);
                hacc2 = __hadd2(hacc2, *(const __half2*)&raw.z);
                hacc3 = __hadd2(hacc3, *(const __half2*)&raw.w);
            }
        }
    }
    float acc[8];
    { float2 f; f = __half22float2(hacc0); acc[0] = f.x; acc[1] = f.y;
      f = __half22float2(hacc1); acc[2] = f.x; acc[3] = f.y;
      f = __half22float2(hacc2); acc[4] = f.x; acc[5] = f.y;
      f = __half22float2(hacc3); acc[6] = f.x; acc[7] = f.y; }
    // reduce across the 8 edge-groups (lane bits 3..5) in f32
    #pragma unroll
    for (int i = 0; i < 8; ++i) {
        float a = acc[i];
        a += __shfl_xor(a, 8, 64);
        a += __shfl_xor(a, 16, 64);
        a += __shfl_xor(a, 32, 64);
        acc[i] = a;
    }
    float dd = 0.f;
    #pragma unroll
    for (int i = 0; i < 8; ++i) dd += acc[i] * acc[i];
    dd += __shfl_xor(dd, 1, 64);
    dd += __shfl_xor(dd, 2, 64);
    dd += __shfl_xor(dd, 4, 64);
    float an = sqrtf(dd);
    float scale = pn[row] / (an + EPS) * dn[row] * (1.0f - ALPHA);

    if (g == 0) {
        long fb = (long)row * D + sub * 8;
        float4 f0a = *(const float4*)(feat0 + fb);
        float4 f0b = *(const float4*)(feat0 + fb + 4);
        float nx[8];
        nx[0] = acc[0] * scale + ALPHA * f0a.x;
        nx[1] = acc[1] * scale + ALPHA * f0a.y;
        nx[2] = acc[2] * scale + ALPHA * f0a.z;
        nx[3] = acc[3] * scale + ALPHA * f0a.w;
        nx[4] = acc[4] * scale + ALPHA * f0b.x;
        nx[5] = acc[5] * scale + ALPHA * f0b.y;
        nx[6] = acc[6] * scale + ALPHA * f0b.z;
        nx[7] = acc[7] * scale + ALPHA * f0b.w;
        if (LAST) {
            float4 o0 = {nx[0], nx[1], nx[2], nx[3]};
            float4 o1 = {nx[4], nx[5], nx[6], nx[7]};
            *(float4*)(out + fb) = o0;
            *(float4*)(out + fb + 4) = o1;
        } else {
            float s = sn[row];
            __half2 h0 = __floats2half2_rn(nx[0] * s, nx[1] * s);
            __half2 h1 = __floats2half2_rn(nx[2] * s, nx[3] * s);
            __half2 h2 = __floats2half2_rn(nx[4] * s, nx[5] * s);
            __half2 h3 = __floats2half2_rn(nx[6] * s, nx[7] * s);
            int4 packed;
            packed.x = *(int*)&h0; packed.y = *(int*)&h1;
            packed.z = *(int*)&h2; packed.w = *(int*)&h3;
            *(int4*)(nexth + fb) = packed;
            float nn = 0.f;
            #pragma unroll
            for (int i = 0; i < 8; ++i) nn += nx[i] * nx[i];
            nn += __shfl_xor(nn, 1, 64);
            nn += __shfl_xor(nn, 2, 64);
            nn += __shfl_xor(nn, 4, 64);
            if (sub == 0) npn[row] = s * sqrtf(nn);
        }
    }
}

extern "C" void kernel_launch(void* const* d_in, const int* in_sizes, int n_in,
                              void* d_out, int out_size, void* d_ws, size_t ws_size,
                              hipStream_t stream) {
    const float* feat = (const float*)d_in[0];
    const int*   src  = (const int*)d_in[1];
    const int*   dst  = (const int*)d_in[2];
    float* out = (float*)d_out;

    int n = in_sizes[0] / D;      // 100000
    int E = in_sizes[1];          // 3200000

    int nbuck = (n + 255) >> BUCK_SH;        // 391 (<= 512 required)
    int nblk  = (E + CH - 1) / CH;           // 391 (<= 512 required)
    int m     = nbuck * nblk;
    // src-range shift: ranges = ((n-1)>>rsh)+1 <= 8
    int rsh = 0;
    while (((n - 1) >> rsh) >= 8) ++rsh;     // n=100000 -> rsh=14 (7 ranges of 16384)

    // workspace layout (4B units for the small arrays)
    int* hist_d  = (int*)d_ws;               // m
    int* hist_s  = hist_d + m;               // m
    int* sbase_d = hist_s + m;               // m+1
    int* sbase_s = sbase_d + m + 1;          // m+1
    int* tot_d   = sbase_s + m + 1;          // 512
    int* tot_s   = tot_d + 512;              // 512
    int* base_d  = tot_s + 512;              // 512
    int* base_s  = base_d + 512;             // 512
    int* rowptr  = base_s + 512;             // n+1
    float* sn    = (float*)(rowptr + n + 1); // n
    float* dn    = sn + n;                   // n
    float* pn_a  = dn + n;                   // n
    float* pn_b  = pn_a + n;                 // n

    // region P (256B-aligned): packed pairs (E u32), later aliased by the two
    // f16 ping-pong feat buffers (2 * n*D halves = 25.6 MB >= 12.8 MB)
    size_t used4 = (size_t)(4 * m + 2) + 2048 + 5 * (size_t)n + 1;
    size_t offP  = (used4 * 4 + 255) & ~(size_t)255;
    unsigned* pairs  = (unsigned*)((char*)d_ws + offP);
    __half* scaled_a = (__half*)((char*)d_ws + offP);          // n*D halves
    __half* scaled_b = scaled_a + (size_t)n * D;               // n*D halves (keeps 256B align)
    size_t szP = 2 * (size_t)n * D * sizeof(__half);           // 25.6 MB (covers pairs 12.8 MB)
    // region Q (256B-aligned): skeys (E u8), later aliased by csr (E u32)
    size_t offQ = (offP + szP + 255) & ~(size_t)255;
    unsigned char* skeys = (unsigned char*)d_ws + offQ;
    int* csr = (int*)((char*)d_ws + offQ);

    int eblocks = nblk;
    // 1. coarse histograms (no global atomics)
    hist_kernel<<<eblocks, 256, 0, stream>>>(src, dst, hist_d, hist_s, nbuck, nblk, E);
    // 2. hierarchical exclusive scan of both [bucket][block] matrices
    bucket_total_kernel<<<nbuck, 256, 0, stream>>>(hist_d, hist_s, tot_d, tot_s, nblk);
    base_scan_kernel<<<1, 512, 0, stream>>>(tot_d, tot_s, base_d, base_s, nbuck);
    row_scan_kernel<<<nbuck, 512, 0, stream>>>(hist_d, hist_s, base_d, base_s,
                                               sbase_d, sbase_s, nblk, E, m);
    // 3. scatter edges into bucket-grouped arrays (packed u32 pairs, u8 skeys)
    scatter_kernel<<<eblocks, 256, 0, stream>>>(src, dst, sbase_d, sbase_s, pairs, skeys,
                                                nbuck, nblk, E);
    // 4. fused build: sn, dn, rowptr, csr sorted by (dst, src-range)
    build_kernel<<<nbuck, 256, 0, stream>>>(pairs, sbase_d, skeys, sbase_s,
                                            rowptr, csr, dn, sn, nbuck, nblk, n, E, rsh);

    // 5. propagation: prescale + 3 fused iterations (f16 ping-pong aliases pairs)
    int blocks = (n + 3) / 4;  // 4 waves per 256-thread block, wave per row
    prescale_kernel<<<blocks, 256, 0, stream>>>(feat, sn, scaled_a, pn_a, n);
    iter_kernel<0><<<blocks, 256, 0, stream>>>(scaled_a, feat, rowptr, csr, pn_a, dn, sn,
                                               scaled_b, pn_b, nullptr, n);
    iter_kernel<0><<<blocks, 256, 0, stream>>>(scaled_b, feat, rowptr, csr, pn_b, dn, sn,
                                               scaled_a, pn_a, nullptr, n);
    iter_kernel<1><<<blocks, 256, 0, stream>>>(scaled_a, feat, rowptr, csr, pn_a, dn, sn,
                                               nullptr, nullptr, out, n);
}

// Round 13
// 301.614 us; speedup vs baseline: 1.1741x; 1.1741x over previous
//
#include <hip/hip_runtime.h>
#include <hip/hip_fp16.h>
#include <math.h>

#define ALPHA 0.1f
#define EPS 1e-6f
#define D 64
#define CH 8192      // edges per block in hist/scatter kernels
#define BUCK_SH 8    // 256 nodes per bucket (nbuck = ceil(n/256) must be <= 512)

// --- per-block coarse histograms, per-wave sub-histograms (conflict /4) -----
__global__ void hist_kernel(const int* __restrict__ src, const int* __restrict__ dst,
                            int* __restrict__ hist_d, int* __restrict__ hist_s,
                            int nbuck, int nblk, int E) {
    __shared__ int hd[4][512], hs[4][512];
    int t = threadIdx.x, b = blockIdx.x, w = t >> 6;
    for (int u = t; u < 512; u += 256) {
        hd[0][u] = 0; hd[1][u] = 0; hd[2][u] = 0; hd[3][u] = 0;
        hs[0][u] = 0; hs[1][u] = 0; hs[2][u] = 0; hs[3][u] = 0;
    }
    __syncthreads();
    int beg = b * CH, end = min(beg + CH, E);
    for (int e = beg + t; e < end; e += 256) {
        atomicAdd(&hd[w][dst[e] >> BUCK_SH], 1);
        atomicAdd(&hs[w][src[e] >> BUCK_SH], 1);
    }
    __syncthreads();
    for (int u = t; u < nbuck; u += 256) {
        hist_d[u * nblk + b] = hd[0][u] + hd[1][u] + hd[2][u] + hd[3][u];
        hist_s[u * nblk + b] = hs[0][u] + hs[1][u] + hs[2][u] + hs[3][u];
    }
}

// --- stage 1: per-bucket totals (one block per bucket, coalesced row sum) ---
__global__ void bucket_total_kernel(const int* __restrict__ hist_d, const int* __restrict__ hist_s,
                                    int* __restrict__ tot_d, int* __restrict__ tot_s, int nblk) {
    __shared__ int rd[256], rs[256];
    int u = blockIdx.x, t = threadIdx.x;
    int sd = 0, ss = 0;
    for (int b = t; b < nblk; b += 256) {
        sd += hist_d[u * nblk + b];
        ss += hist_s[u * nblk + b];
    }
    rd[t] = sd; rs[t] = ss;
    __syncthreads();
    for (int off = 128; off; off >>= 1) {
        if (t < off) { rd[t] += rd[t + off]; rs[t] += rs[t + off]; }
        __syncthreads();
    }
    if (t == 0) { tot_d[u] = rd[0]; tot_s[u] = rs[0]; }
}

// --- stage 2: exclusive scan of bucket totals (single 512-thread block) -----
__global__ void base_scan_kernel(const int* __restrict__ tot_d, const int* __restrict__ tot_s,
                                 int* __restrict__ base_d, int* __restrict__ base_s, int nbuck) {
    __shared__ int a[512], b[512];
    int t = threadIdx.x;
    int vd = (t < nbuck) ? tot_d[t] : 0;
    int vs = (t < nbuck) ? tot_s[t] : 0;
    a[t] = vd; b[t] = vs;
    __syncthreads();
    for (int off = 1; off < 512; off <<= 1) {
        int av = (t >= off) ? a[t - off] : 0;
        int bv = (t >= off) ? b[t - off] : 0;
        __syncthreads();
        a[t] += av; b[t] += bv;
        __syncthreads();
    }
    if (t < nbuck) {
        base_d[t] = a[t] - vd;   // exclusive
        base_s[t] = b[t] - vs;
    }
}

// --- stage 3: per-bucket row scan + bucket base -> scatter bases ------------
__global__ void row_scan_kernel(const int* __restrict__ hist_d, const int* __restrict__ hist_s,
                                const int* __restrict__ base_d, const int* __restrict__ base_s,
                                int* __restrict__ sbase_d, int* __restrict__ sbase_s,
                                int nblk, int E, int m) {
    __shared__ int a[512], b[512];
    int u = blockIdx.x, t = threadIdx.x;
    int hd = (t < nblk) ? hist_d[u * nblk + t] : 0;
    int hs = (t < nblk) ? hist_s[u * nblk + t] : 0;
    a[t] = hd; b[t] = hs;
    __syncthreads();
    for (int off = 1; off < 512; off <<= 1) {
        int av = (t >= off) ? a[t - off] : 0;
        int bv = (t >= off) ? b[t - off] : 0;
        __syncthreads();
        a[t] += av; b[t] += bv;
        __syncthreads();
    }
    if (t < nblk) {
        sbase_d[u * nblk + t] = base_d[u] + a[t] - hd;
        sbase_s[u * nblk + t] = base_s[u] + b[t] - hs;
    }
    if (u == 0 && t == 0) { sbase_d[m] = E; sbase_s[m] = E; }
}

// --- scatter with LDS binning: coalesced segment dump to final positions ----
// pairs packed: (dst & 255) << 24 | src   (requires n < 2^24)
__global__ void scatter_kernel(const int* __restrict__ src, const int* __restrict__ dst,
                               const int* __restrict__ sbase_d, const int* __restrict__ sbase_s,
                               unsigned* __restrict__ pairs, unsigned char* __restrict__ skeys,
                               int nbuck, int nblk, int E) {
    __shared__ unsigned sp[CH];        // pairs binned by dst-bucket (32 KB)
    __shared__ unsigned char sk[CH];   // src lo-bytes binned by src-bucket (8 KB)
    __shared__ int hd[512], hs[512];   // counts, then running placement counters
    __shared__ int ld[512], ls[512];   // pristine exclusive scans
    __shared__ int ts[256];
    int t = threadIdx.x, b = blockIdx.x;
    for (int u = t; u < 512; u += 256) { hd[u] = 0; hs[u] = 0; }
    __syncthreads();
    int beg = b * CH, end = min(beg + CH, E), cnt = end - beg;
    for (int e = beg + t; e < end; e += 256) {
        atomicAdd(&hd[dst[e] >> BUCK_SH], 1);
        atomicAdd(&hs[src[e] >> BUCK_SH], 1);
    }
    __syncthreads();
    // exclusive scans of hd->ld and hs->ls (512 entries, 2 per thread)
    int v0 = hd[2 * t], v1 = hd[2 * t + 1];
    int w0 = hs[2 * t], w1 = hs[2 * t + 1];
    ts[t] = v0 + v1;
    __syncthreads();
    for (int off = 1; off < 256; off <<= 1) {
        int v = (t >= off) ? ts[t - off] : 0;
        __syncthreads();
        ts[t] += v;
        __syncthreads();
    }
    int based = (t == 0) ? 0 : ts[t - 1];
    ld[2 * t] = based; ld[2 * t + 1] = based + v0;
    __syncthreads();
    ts[t] = w0 + w1;
    __syncthreads();
    for (int off = 1; off < 256; off <<= 1) {
        int v = (t >= off) ? ts[t - off] : 0;
        __syncthreads();
        ts[t] += v;
        __syncthreads();
    }
    int bases = (t == 0) ? 0 : ts[t - 1];
    ls[2 * t] = bases; ls[2 * t + 1] = bases + w0;
    __syncthreads();
    // init running counters from scans
    hd[2 * t] = ld[2 * t]; hd[2 * t + 1] = ld[2 * t + 1];
    hs[2 * t] = ls[2 * t]; hs[2 * t + 1] = ls[2 * t + 1];
    __syncthreads();
    // placement pass (re-read edges: L1/L2-hot)
    for (int e = beg + t; e < end; e += 256) {
        int dv = dst[e], sv = src[e];
        int p = atomicAdd(&hd[dv >> BUCK_SH], 1);
        sp[p] = ((unsigned)(dv & 255) << 24) | (unsigned)sv;
        int q = atomicAdd(&hs[sv >> BUCK_SH], 1);
        sk[q] = (unsigned char)(sv & 255);
    }
    __syncthreads();
    // dump: element i -> bucket via binary search in pristine scans; coalesced runs
    for (int i = t; i < cnt; i += 256) {
        unsigned pv = sp[i];
        int lo = 0;
        #pragma unroll
        for (int s = 256; s; s >>= 1) { int mid = lo + s; if (mid < 512 && ld[mid] <= i) lo = mid; }
        pairs[sbase_d[lo * nblk + b] + (i - ld[lo])] = pv;
        unsigned char kv = sk[i];
        int lo2 = 0;
        #pragma unroll
        for (int s = 256; s; s >>= 1) { int mid = lo2 + s; if (mid < 512 && ls[mid] <= i) lo2 = mid; }
        skeys[sbase_s[lo2 * nblk + b] + (i - ls[lo2])] = kv;
    }
}

// --- per-bucket build (fused src-deg + dst build): sn, dn, rowptr, csr ------
__global__ void build_kernel(const unsigned* __restrict__ pairs, const int* __restrict__ sbase_d,
                             const unsigned char* __restrict__ skeys, const int* __restrict__ sbase_s,
                             int* __restrict__ rowptr, int* __restrict__ csr,
                             float* __restrict__ dn, float* __restrict__ sn,
                             int nbuck, int nblk, int n, int E) {
    __shared__ int lh[256], le[256], cnt[256], lhs[256];
    int t = threadIdx.x, u = blockIdx.x;
    lh[t] = 0; cnt[t] = 0; lhs[t] = 0;
    __syncthreads();
    // src-side per-node out-degree
    int sb = sbase_s[u * nblk];
    int se = sbase_s[(u + 1) * nblk];
    for (int i = sb + t; i < se; i += 256) atomicAdd(&lhs[skeys[i]], 1);
    // dst-side per-node in-degree
    int beg = sbase_d[u * nblk];
    int end = sbase_d[(u + 1) * nblk];
    for (int i = beg + t; i < end; i += 256) atomicAdd(&lh[pairs[i] >> 24], 1);
    __syncthreads();
    int c0 = lh[t];
    for (int off = 1; off < 256; off <<= 1) {
        int x = (t >= off) ? lh[t - off] : 0;
        __syncthreads();
        lh[t] += x;
        __syncthreads();
    }
    le[t] = lh[t] - c0;
    __syncthreads();
    int node = (u << BUCK_SH) + t;
    if (node < n) {
        rowptr[node] = beg + le[t];
        dn[node] = rsqrtf(fmaxf((float)c0, 1.0f));
        sn[node] = rsqrtf(fmaxf((float)lhs[t], 1.0f));
    }
    if (u == nbuck - 1 && t == 0) rowptr[n] = E;
    for (int i = beg + t; i < end; i += 256) {
        unsigned pr = pairs[i];
        int bb = pr >> 24;
        int p = atomicAdd(&cnt[bb], 1);
        csr[beg + le[bb] + p] = (int)(pr & 0xFFFFFFu);
    }
}

// --- seed: scaled_h[row] = feat*sn[row] (f16), pn[row] = sn*||feat[row]|| ---
__global__ void prescale_kernel(const float* __restrict__ feat, const float* __restrict__ sn,
                                __half* __restrict__ outh, float* __restrict__ pn, int n) {
    int row  = blockIdx.x * (blockDim.x >> 6) + (threadIdx.x >> 6);
    int lane = threadIdx.x & 63;
    if (row >= n) return;
    float x = feat[(long)row * D + lane];
    float ss = x * x;
    #pragma unroll
    for (int off = 32; off; off >>= 1) ss += __shfl_xor(ss, off, 64);
    float s = sn[row];
    float v = x * s;
    float vp = __shfl_xor(v, 1, 64);
    if (!(lane & 1)) {
        *(__half2*)(outh + (long)row * D + lane) = __floats2half2_rn(v, vp);
    }
    if (lane == 0) pn[row] = s * sqrtf(ss);
}

// --- fused iteration: one wave per dst row, packed-f16 row accumulation -----
// lane = (g,sub): g (0..7) = edge slot, sub (0..7) = 16B (8-half) column slice
template <int LAST>
__global__ void iter_kernel(const __half* __restrict__ cur, const float* __restrict__ feat0,
                            const int* __restrict__ rowptr, const int* __restrict__ csr_src,
                            const float* __restrict__ pn, const float* __restrict__ dn,
                            const float* __restrict__ sn,
                            __half* __restrict__ nexth, float* __restrict__ npn,
                            float* __restrict__ out, int n) {
    int row  = blockIdx.x * (blockDim.x >> 6) + (threadIdx.x >> 6);
    int lane = threadIdx.x & 63;
    if (row >= n) return;
    int g = lane >> 3, sub = lane & 7;

    __half2 hz = __float2half2_rn(0.f);
    __half2 hacc0 = hz, hacc1 = hz, hacc2 = hz, hacc3 = hz;
    int beg = rowptr[row], end = rowptr[row + 1];
    for (int base = beg; base < end; base += 64) {
        int m = end - base; if (m > 64) m = 64;
        int s_l = (lane < m) ? csr_src[base + lane] : 0;
        int nfull = m >> 3;        // steps where all 8 groups have a valid edge
        #pragma unroll 4
        for (int j = 0; j < nfull; ++j) {
            int s = __shfl(s_l, j * 8 + g, 64);
            int4 raw = *(const int4*)(cur + (long)s * D + sub * 8);
            hacc0 = __hadd2(hacc0, *(__half2*)&raw.x);
            hacc1 = __hadd2(hacc1, *(__half2*)&raw.y);
            hacc2 = __hadd2(hacc2, *(__half2*)&raw.z);
            hacc3 = __hadd2(hacc3, *(__half2*)&raw.w);
        }
        int e = nfull * 8 + g;     // tail step (e <= 63)
        int s = __shfl(s_l, e, 64);
        if (e < m) {
            int4 raw = *(const int4*)(cur + (long)s * D + sub * 8);
            hacc0 = __hadd2(hacc0, *(__half2*)&raw.x);
            hacc1 = __hadd2(hacc1, *(__half2*)&raw.y);
            hacc2 = __hadd2(hacc2, *(__half2*)&raw.z);
            hacc3 = __hadd2(hacc3, *(__half2*)&raw.w);
        }
    }
    float acc[8];
    { float2 f; f = __half22float2(hacc0); acc[0] = f.x; acc[1] = f.y;
      f = __half22float2(hacc1); acc[2] = f.x; acc[3] = f.y;
      f = __half22float2(hacc2); acc[4] = f.x; acc[5] = f.y;
      f = __half22float2(hacc3); acc[6] = f.x; acc[7] = f.y; }
    // reduce across the 8 edge-groups (lane bits 3..5) in f32
    #pragma unroll
    for (int i = 0; i < 8; ++i) {
        float a = acc[i];
        a += __shfl_xor(a, 8, 64);
        a += __shfl_xor(a, 16, 64);
        a += __shfl_xor(a, 32, 64);
        acc[i] = a;
    }
    float dd = 0.f;
    #pragma unroll
    for (int i = 0; i < 8; ++i) dd += acc[i] * acc[i];
    dd += __shfl_xor(dd, 1, 64);
    dd += __shfl_xor(dd, 2, 64);
    dd += __shfl_xor(dd, 4, 64);
    float an = sqrtf(dd);
    float scale = pn[row] / (an + EPS) * dn[row] * (1.0f - ALPHA);

    if (g == 0) {
        long fb = (long)row * D + sub * 8;
        float4 f0a = *(const float4*)(feat0 + fb);
        float4 f0b = *(const float4*)(feat0 + fb + 4);
        float nx[8];
        nx[0] = acc[0] * scale + ALPHA * f0a.x;
        nx[1] = acc[1] * scale + ALPHA * f0a.y;
        nx[2] = acc[2] * scale + ALPHA * f0a.z;
        nx[3] = acc[3] * scale + ALPHA * f0a.w;
        nx[4] = acc[4] * scale + ALPHA * f0b.x;
        nx[5] = acc[5] * scale + ALPHA * f0b.y;
        nx[6] = acc[6] * scale + ALPHA * f0b.z;
        nx[7] = acc[7] * scale + ALPHA * f0b.w;
        if (LAST) {
            float4 o0 = {nx[0], nx[1], nx[2], nx[3]};
            float4 o1 = {nx[4], nx[5], nx[6], nx[7]};
            *(float4*)(out + fb) = o0;
            *(float4*)(out + fb + 4) = o1;
        } else {
            float s = sn[row];
            __half2 h0 = __floats2half2_rn(nx[0] * s, nx[1] * s);
            __half2 h1 = __floats2half2_rn(nx[2] * s, nx[3] * s);
            __half2 h2 = __floats2half2_rn(nx[4] * s, nx[5] * s);
            __half2 h3 = __floats2half2_rn(nx[6] * s, nx[7] * s);
            int4 packed;
            packed.x = *(int*)&h0; packed.y = *(int*)&h1;
            packed.z = *(int*)&h2; packed.w = *(int*)&h3;
            *(int4*)(nexth + fb) = packed;
            float nn = 0.f;
            #pragma unroll
            for (int i = 0; i < 8; ++i) nn += nx[i] * nx[i];
            nn += __shfl_xor(nn, 1, 64);
            nn += __shfl_xor(nn, 2, 64);
            nn += __shfl_xor(nn, 4, 64);
            if (sub == 0) npn[row] = s * sqrtf(nn);
        }
    }
}

extern "C" void kernel_launch(void* const* d_in, const int* in_sizes, int n_in,
                              void* d_out, int out_size, void* d_ws, size_t ws_size,
                              hipStream_t stream) {
    const float* feat = (const float*)d_in[0];
    const int*   src  = (const int*)d_in[1];
    const int*   dst  = (const int*)d_in[2];
    float* out = (float*)d_out;

    int n = in_sizes[0] / D;      // 100000
    int E = in_sizes[1];          // 3200000

    int nbuck = (n + 255) >> BUCK_SH;        // 391 (<= 512 required)
    int nblk  = (E + CH - 1) / CH;           // 391 (<= 512 required)
    int m     = nbuck * nblk;

    // workspace layout (4B units for the small arrays)
    int* hist_d  = (int*)d_ws;               // m
    int* hist_s  = hist_d + m;               // m
    int* sbase_d = hist_s + m;               // m+1
    int* sbase_s = sbase_d + m + 1;          // m+1
    int* tot_d   = sbase_s + m + 1;          // 512
    int* tot_s   = tot_d + 512;              // 512
    int* base_d  = tot_s + 512;              // 512
    int* base_s  = base_d + 512;             // 512
    int* rowptr  = base_s + 512;             // n+1
    float* sn    = (float*)(rowptr + n + 1); // n
    float* dn    = sn + n;                   // n
    float* pn_a  = dn + n;                   // n
    float* pn_b  = pn_a + n;                 // n

    // region P (256B-aligned): packed pairs (E u32), later aliased by the two
    // f16 ping-pong feat buffers (2 * n*D halves = 25.6 MB >= 12.8 MB)
    size_t used4 = (size_t)(4 * m + 2) + 2048 + 5 * (size_t)n + 1;
    size_t offP  = (used4 * 4 + 255) & ~(size_t)255;
    unsigned* pairs  = (unsigned*)((char*)d_ws + offP);
    __half* scaled_a = (__half*)((char*)d_ws + offP);          // n*D halves
    __half* scaled_b = scaled_a + (size_t)n * D;               // n*D halves (keeps 256B align)
    size_t szP = 2 * (size_t)n * D * sizeof(__half);           // 25.6 MB (covers pairs 12.8 MB)
    // region Q (256B-aligned): skeys (E u8), later aliased by csr (E u32)
    size_t offQ = (offP + szP + 255) & ~(size_t)255;
    unsigned char* skeys = (unsigned char*)d_ws + offQ;
    int* csr = (int*)((char*)d_ws + offQ);

    int eblocks = nblk;
    // 1. coarse histograms (per-wave sub-hist, no global atomics)
    hist_kernel<<<eblocks, 256, 0, stream>>>(src, dst, hist_d, hist_s, nbuck, nblk, E);
    // 2. hierarchical exclusive scan of both [bucket][block] matrices
    bucket_total_kernel<<<nbuck, 256, 0, stream>>>(hist_d, hist_s, tot_d, tot_s, nblk);
    base_scan_kernel<<<1, 512, 0, stream>>>(tot_d, tot_s, base_d, base_s, nbuck);
    row_scan_kernel<<<nbuck, 512, 0, stream>>>(hist_d, hist_s, base_d, base_s,
                                               sbase_d, sbase_s, nblk, E, m);
    // 3. scatter with LDS binning: coalesced dump into bucket-grouped arrays
    scatter_kernel<<<eblocks, 256, 0, stream>>>(src, dst, sbase_d, sbase_s, pairs, skeys,
                                                nbuck, nblk, E);
    // 4. fused build: sn, dn, rowptr, csr (csr aliases skeys; pairs consumed here)
    build_kernel<<<nbuck, 256, 0, stream>>>(pairs, sbase_d, skeys, sbase_s,
                                            rowptr, csr, dn, sn, nbuck, nblk, n, E);

    // 5. propagation: prescale + 3 fused iterations (f16 ping-pong aliases pairs)
    int blocks = (n + 3) / 4;  // 4 waves per 256-thread block, wave per row
    prescale_kernel<<<blocks, 256, 0, stream>>>(feat, sn, scaled_a, pn_a, n);
    iter_kernel<0><<<blocks, 256, 0, stream>>>(scaled_a, feat, rowptr, csr, pn_a, dn, sn,
                                               scaled_b, pn_b, nullptr, n);
    iter_kernel<0><<<blocks, 256, 0, stream>>>(scaled_b, feat, rowptr, csr, pn_b, dn, sn,
                                               scaled_a, pn_a, nullptr, n);
    iter_kernel<1><<<blocks, 256, 0, stream>>>(scaled_a, feat, rowptr, csr, pn_a, dn, sn,
                                               nullptr, nullptr, out, n);
}

// Round 14
// 294.872 us; speedup vs baseline: 1.2009x; 1.0229x over previous
//
#include <hip/hip_runtime.h>
#include <hip/hip_fp16.h>
#include <math.h>

#define ALPHA 0.1f
#define EPS 1e-6f
#define D 64
#define CH 8192      // edges per block in hist/scatter kernels
#define BUCK_SH 8    // 256 nodes per bucket (nbuck = ceil(n/256) must be <= 512)

// --- per-block coarse histograms, per-wave sub-histograms (conflict /4) -----
__global__ void hist_kernel(const int* __restrict__ src, const int* __restrict__ dst,
                            int* __restrict__ hist_d, int* __restrict__ hist_s,
                            int nbuck, int nblk, int E) {
    __shared__ int hd[4][512], hs[4][512];
    int t = threadIdx.x, b = blockIdx.x, w = t >> 6;
    for (int u = t; u < 512; u += 256) {
        hd[0][u] = 0; hd[1][u] = 0; hd[2][u] = 0; hd[3][u] = 0;
        hs[0][u] = 0; hs[1][u] = 0; hs[2][u] = 0; hs[3][u] = 0;
    }
    __syncthreads();
    int beg = b * CH, end = min(beg + CH, E);
    for (int e = beg + t; e < end; e += 256) {
        atomicAdd(&hd[w][dst[e] >> BUCK_SH], 1);
        atomicAdd(&hs[w][src[e] >> BUCK_SH], 1);
    }
    __syncthreads();
    for (int u = t; u < nbuck; u += 256) {
        hist_d[u * nblk + b] = hd[0][u] + hd[1][u] + hd[2][u] + hd[3][u];
        hist_s[u * nblk + b] = hs[0][u] + hs[1][u] + hs[2][u] + hs[3][u];
    }
}

// --- stage 1: per-bucket totals (one block per bucket, coalesced row sum) ---
__global__ void bucket_total_kernel(const int* __restrict__ hist_d, const int* __restrict__ hist_s,
                                    int* __restrict__ tot_d, int* __restrict__ tot_s, int nblk) {
    __shared__ int rd[256], rs[256];
    int u = blockIdx.x, t = threadIdx.x;
    int sd = 0, ss = 0;
    for (int b = t; b < nblk; b += 256) {
        sd += hist_d[u * nblk + b];
        ss += hist_s[u * nblk + b];
    }
    rd[t] = sd; rs[t] = ss;
    __syncthreads();
    for (int off = 128; off; off >>= 1) {
        if (t < off) { rd[t] += rd[t + off]; rs[t] += rs[t + off]; }
        __syncthreads();
    }
    if (t == 0) { tot_d[u] = rd[0]; tot_s[u] = rs[0]; }
}

// --- stage 2: exclusive scan of bucket totals (single 512-thread block) -----
__global__ void base_scan_kernel(const int* __restrict__ tot_d, const int* __restrict__ tot_s,
                                 int* __restrict__ base_d, int* __restrict__ base_s, int nbuck) {
    __shared__ int a[512], b[512];
    int t = threadIdx.x;
    int vd = (t < nbuck) ? tot_d[t] : 0;
    int vs = (t < nbuck) ? tot_s[t] : 0;
    a[t] = vd; b[t] = vs;
    __syncthreads();
    for (int off = 1; off < 512; off <<= 1) {
        int av = (t >= off) ? a[t - off] : 0;
        int bv = (t >= off) ? b[t - off] : 0;
        __syncthreads();
        a[t] += av; b[t] += bv;
        __syncthreads();
    }
    if (t < nbuck) {
        base_d[t] = a[t] - vd;   // exclusive
        base_s[t] = b[t] - vs;
    }
}

// --- stage 3: per-bucket row scan + bucket base -> scatter bases ------------
__global__ void row_scan_kernel(const int* __restrict__ hist_d, const int* __restrict__ hist_s,
                                const int* __restrict__ base_d, const int* __restrict__ base_s,
                                int* __restrict__ sbase_d, int* __restrict__ sbase_s,
                                int nblk, int E, int m) {
    __shared__ int a[512], b[512];
    int u = blockIdx.x, t = threadIdx.x;
    int hd = (t < nblk) ? hist_d[u * nblk + t] : 0;
    int hs = (t < nblk) ? hist_s[u * nblk + t] : 0;
    a[t] = hd; b[t] = hs;
    __syncthreads();
    for (int off = 1; off < 512; off <<= 1) {
        int av = (t >= off) ? a[t - off] : 0;
        int bv = (t >= off) ? b[t - off] : 0;
        __syncthreads();
        a[t] += av; b[t] += bv;
        __syncthreads();
    }
    if (t < nblk) {
        sbase_d[u * nblk + t] = base_d[u] + a[t] - hd;
        sbase_s[u * nblk + t] = base_s[u] + b[t] - hs;
    }
    if (u == 0 && t == 0) { sbase_d[m] = E; sbase_s[m] = E; }
}

// --- scatter with LDS binning: coalesced segment dump to final positions ----
// pairs packed: (dst & 255) << 24 | src   (requires n < 2^24)
__global__ void scatter_kernel(const int* __restrict__ src, const int* __restrict__ dst,
                               const int* __restrict__ sbase_d, const int* __restrict__ sbase_s,
                               unsigned* __restrict__ pairs, unsigned char* __restrict__ skeys,
                               int nbuck, int nblk, int E) {
    __shared__ unsigned sp[CH];        // pairs binned by dst-bucket (32 KB)
    __shared__ unsigned char sk[CH];   // src lo-bytes binned by src-bucket (8 KB)
    __shared__ int hd[512], hs[512];   // counts, then running placement counters
    __shared__ int ld[512], ls[512];   // pristine exclusive scans
    __shared__ int ts[256];
    int t = threadIdx.x, b = blockIdx.x;
    for (int u = t; u < 512; u += 256) { hd[u] = 0; hs[u] = 0; }
    __syncthreads();
    int beg = b * CH, end = min(beg + CH, E), cnt = end - beg;
    for (int e = beg + t; e < end; e += 256) {
        atomicAdd(&hd[dst[e] >> BUCK_SH], 1);
        atomicAdd(&hs[src[e] >> BUCK_SH], 1);
    }
    __syncthreads();
    // exclusive scans of hd->ld and hs->ls (512 entries, 2 per thread)
    int v0 = hd[2 * t], v1 = hd[2 * t + 1];
    int w0 = hs[2 * t], w1 = hs[2 * t + 1];
    ts[t] = v0 + v1;
    __syncthreads();
    for (int off = 1; off < 256; off <<= 1) {
        int v = (t >= off) ? ts[t - off] : 0;
        __syncthreads();
        ts[t] += v;
        __syncthreads();
    }
    int based = (t == 0) ? 0 : ts[t - 1];
    ld[2 * t] = based; ld[2 * t + 1] = based + v0;
    __syncthreads();
    ts[t] = w0 + w1;
    __syncthreads();
    for (int off = 1; off < 256; off <<= 1) {
        int v = (t >= off) ? ts[t - off] : 0;
        __syncthreads();
        ts[t] += v;
        __syncthreads();
    }
    int bases = (t == 0) ? 0 : ts[t - 1];
    ls[2 * t] = bases; ls[2 * t + 1] = bases + w0;
    __syncthreads();
    // init running counters from scans
    hd[2 * t] = ld[2 * t]; hd[2 * t + 1] = ld[2 * t + 1];
    hs[2 * t] = ls[2 * t]; hs[2 * t + 1] = ls[2 * t + 1];
    __syncthreads();
    // placement pass (re-read edges: L1/L2-hot)
    for (int e = beg + t; e < end; e += 256) {
        int dv = dst[e], sv = src[e];
        int p = atomicAdd(&hd[dv >> BUCK_SH], 1);
        sp[p] = ((unsigned)(dv & 255) << 24) | (unsigned)sv;
        int q = atomicAdd(&hs[sv >> BUCK_SH], 1);
        sk[q] = (unsigned char)(sv & 255);
    }
    __syncthreads();
    // dump: element i -> bucket via binary search in pristine scans; coalesced runs
    for (int i = t; i < cnt; i += 256) {
        unsigned pv = sp[i];
        int lo = 0;
        #pragma unroll
        for (int s = 256; s; s >>= 1) { int mid = lo + s; if (mid < 512 && ld[mid] <= i) lo = mid; }
        pairs[sbase_d[lo * nblk + b] + (i - ld[lo])] = pv;
        unsigned char kv = sk[i];
        int lo2 = 0;
        #pragma unroll
        for (int s = 256; s; s >>= 1) { int mid = lo2 + s; if (mid < 512 && ls[mid] <= i) lo2 = mid; }
        skeys[sbase_s[lo2 * nblk + b] + (i - ls[lo2])] = kv;
    }
}

// --- per-bucket build (fused src-deg + dst build): sn, dn, rowptr, csr ------
__global__ void build_kernel(const unsigned* __restrict__ pairs, const int* __restrict__ sbase_d,
                             const unsigned char* __restrict__ skeys, const int* __restrict__ sbase_s,
                             int* __restrict__ rowptr, int* __restrict__ csr,
                             float* __restrict__ dn, float* __restrict__ sn,
                             int nbuck, int nblk, int n, int E) {
    __shared__ int lh[256], le[256], cnt[256], lhs[256];
    int t = threadIdx.x, u = blockIdx.x;
    lh[t] = 0; cnt[t] = 0; lhs[t] = 0;
    __syncthreads();
    // src-side per-node out-degree
    int sb = sbase_s[u * nblk];
    int se = sbase_s[(u + 1) * nblk];
    for (int i = sb + t; i < se; i += 256) atomicAdd(&lhs[skeys[i]], 1);
    // dst-side per-node in-degree
    int beg = sbase_d[u * nblk];
    int end = sbase_d[(u + 1) * nblk];
    for (int i = beg + t; i < end; i += 256) atomicAdd(&lh[pairs[i] >> 24], 1);
    __syncthreads();
    int c0 = lh[t];
    for (int off = 1; off < 256; off <<= 1) {
        int x = (t >= off) ? lh[t - off] : 0;
        __syncthreads();
        lh[t] += x;
        __syncthreads();
    }
    le[t] = lh[t] - c0;
    __syncthreads();
    int node = (u << BUCK_SH) + t;
    if (node < n) {
        rowptr[node] = beg + le[t];
        dn[node] = rsqrtf(fmaxf((float)c0, 1.0f));
        sn[node] = rsqrtf(fmaxf((float)lhs[t], 1.0f));
    }
    if (u == nbuck - 1 && t == 0) rowptr[n] = E;
    for (int i = beg + t; i < end; i += 256) {
        unsigned pr = pairs[i];
        int bb = pr >> 24;
        int p = atomicAdd(&cnt[bb], 1);
        csr[beg + le[bb] + p] = (int)(pr & 0xFFFFFFu);
    }
}

// --- seed: scaled_h[row] = feat*sn[row] (f16), pn[row] = sn*||feat[row]|| ---
__global__ void prescale_kernel(const float* __restrict__ feat, const float* __restrict__ sn,
                                __half* __restrict__ outh, float* __restrict__ pn, int n) {
    int row  = blockIdx.x * (blockDim.x >> 6) + (threadIdx.x >> 6);
    int lane = threadIdx.x & 63;
    if (row >= n) return;
    float x = feat[(long)row * D + lane];
    float ss = x * x;
    #pragma unroll
    for (int off = 32; off; off >>= 1) ss += __shfl_xor(ss, off, 64);
    float s = sn[row];
    float v = x * s;
    float vp = __shfl_xor(v, 1, 64);
    if (!(lane & 1)) {
        *(__half2*)(outh + (long)row * D + lane) = __floats2half2_rn(v, vp);
    }
    if (lane == 0) pn[row] = s * sqrtf(ss);
}

// --- fused iteration: TWO rows per wave (32 lanes each) ---------------------
// lane = (half, g, sub): half (bit5) = which row, g (bits 3..4) = edge slot
// (4 per row), sub (bits 0..2) = 16B column slice. Avg row (32 edges) = 8
// sequential steps/lane, fully unrolled -> 8 gathers in flight (2x MLP).
template <int LAST>
__global__ void iter_kernel(const __half* __restrict__ cur, const float* __restrict__ feat0,
                            const int* __restrict__ rowptr, const int* __restrict__ csr_src,
                            const float* __restrict__ pn, const float* __restrict__ dn,
                            const float* __restrict__ sn,
                            __half* __restrict__ nexth, float* __restrict__ npn,
                            float* __restrict__ out, int n) {
    int wid  = blockIdx.x * (blockDim.x >> 6) + (threadIdx.x >> 6);
    int lane = threadIdx.x & 63;
    int half = lane >> 5;            // which row of the pair
    int h    = lane & 31;
    int g    = h >> 3;               // edge slot 0..3
    int sub  = h & 7;                // 16B column slice
    int row  = wid * 2 + half;
    bool valid = row < n;

    int beg = valid ? rowptr[row] : 0;
    int end = valid ? rowptr[row + 1] : 0;
    int deg = end - beg;
    const int* idx = csr_src + beg;
    unsigned subOff = (unsigned)sub * 16u;

    __half2 hz = __float2half2_rn(0.f);
    __half2 hacc0 = hz, hacc1 = hz, hacc2 = hz, hacc3 = hz;
    for (int base = 0; base < deg; base += 32) {
        int s_l = (base + h < deg) ? idx[base + h] : 0;   // 32 idx per row
        #pragma unroll
        for (int k = 0; k < 8; ++k) {
            int e = base + k * 4 + g;
            int s = __shfl(s_l, (half << 5) | (k * 4 + g), 64);
            if (e < deg) {
                int4 raw = *(const int4*)((const char*)cur + (unsigned)s * 128u + subOff);
                hacc0 = __hadd2(hacc0, *(const __half2*)&raw.x);
                hacc1 = __hadd2(hacc1, *(const __half2*)&raw.y);
                hacc2 = __hadd2(hacc2, *(const __half2*)&raw.z);
                hacc3 = __hadd2(hacc3, *(const __half2*)&raw.w);
            }
        }
    }
    float acc[8];
    { float2 f; f = __half22float2(hacc0); acc[0] = f.x; acc[1] = f.y;
      f = __half22float2(hacc1); acc[2] = f.x; acc[3] = f.y;
      f = __half22float2(hacc2); acc[4] = f.x; acc[5] = f.y;
      f = __half22float2(hacc3); acc[6] = f.x; acc[7] = f.y; }
    // reduce across the 4 edge slots (lane bits 3..4, within the 32-lane half)
    #pragma unroll
    for (int i = 0; i < 8; ++i) {
        float a = acc[i];
        a += __shfl_xor(a, 8, 64);
        a += __shfl_xor(a, 16, 64);
        acc[i] = a;
    }
    float dd = 0.f;
    #pragma unroll
    for (int i = 0; i < 8; ++i) dd += acc[i] * acc[i];
    dd += __shfl_xor(dd, 1, 64);
    dd += __shfl_xor(dd, 2, 64);
    dd += __shfl_xor(dd, 4, 64);
    if (!valid) return;
    float an = sqrtf(dd);
    float scale = pn[row] / (an + EPS) * dn[row] * (1.0f - ALPHA);

    if (g == 0) {
        long fb = (long)row * D + sub * 8;
        float4 f0a = *(const float4*)(feat0 + fb);
        float4 f0b = *(const float4*)(feat0 + fb + 4);
        float nx[8];
        nx[0] = acc[0] * scale + ALPHA * f0a.x;
        nx[1] = acc[1] * scale + ALPHA * f0a.y;
        nx[2] = acc[2] * scale + ALPHA * f0a.z;
        nx[3] = acc[3] * scale + ALPHA * f0a.w;
        nx[4] = acc[4] * scale + ALPHA * f0b.x;
        nx[5] = acc[5] * scale + ALPHA * f0b.y;
        nx[6] = acc[6] * scale + ALPHA * f0b.z;
        nx[7] = acc[7] * scale + ALPHA * f0b.w;
        if (LAST) {
            float4 o0 = {nx[0], nx[1], nx[2], nx[3]};
            float4 o1 = {nx[4], nx[5], nx[6], nx[7]};
            *(float4*)(out + fb) = o0;
            *(float4*)(out + fb + 4) = o1;
        } else {
            float s = sn[row];
            __half2 h0 = __floats2half2_rn(nx[0] * s, nx[1] * s);
            __half2 h1 = __floats2half2_rn(nx[2] * s, nx[3] * s);
            __half2 h2 = __floats2half2_rn(nx[4] * s, nx[5] * s);
            __half2 h3 = __floats2half2_rn(nx[6] * s, nx[7] * s);
            int4 packed;
            packed.x = *(int*)&h0; packed.y = *(int*)&h1;
            packed.z = *(int*)&h2; packed.w = *(int*)&h3;
            *(int4*)(nexth + fb) = packed;
            float nn = 0.f;
            #pragma unroll
            for (int i = 0; i < 8; ++i) nn += nx[i] * nx[i];
            nn += __shfl_xor(nn, 1, 64);
            nn += __shfl_xor(nn, 2, 64);
            nn += __shfl_xor(nn, 4, 64);
            if (sub == 0) npn[row] = s * sqrtf(nn);
        }
    }
}

extern "C" void kernel_launch(void* const* d_in, const int* in_sizes, int n_in,
                              void* d_out, int out_size, void* d_ws, size_t ws_size,
                              hipStream_t stream) {
    const float* feat = (const float*)d_in[0];
    const int*   src  = (const int*)d_in[1];
    const int*   dst  = (const int*)d_in[2];
    float* out = (float*)d_out;

    int n = in_sizes[0] / D;      // 100000
    int E = in_sizes[1];          // 3200000

    int nbuck = (n + 255) >> BUCK_SH;        // 391 (<= 512 required)
    int nblk  = (E + CH - 1) / CH;           // 391 (<= 512 required)
    int m     = nbuck * nblk;

    // workspace layout (4B units for the small arrays)
    int* hist_d  = (int*)d_ws;               // m
    int* hist_s  = hist_d + m;               // m
    int* sbase_d = hist_s + m;               // m+1
    int* sbase_s = sbase_d + m + 1;          // m+1
    int* tot_d   = sbase_s + m + 1;          // 512
    int* tot_s   = tot_d + 512;              // 512
    int* base_d  = tot_s + 512;              // 512
    int* base_s  = base_d + 512;             // 512
    int* rowptr  = base_s + 512;             // n+1
    float* sn    = (float*)(rowptr + n + 1); // n
    float* dn    = sn + n;                   // n
    float* pn_a  = dn + n;                   // n
    float* pn_b  = pn_a + n;                 // n

    // region P (256B-aligned): packed pairs (E u32), later aliased by the two
    // f16 ping-pong feat buffers (2 * n*D halves = 25.6 MB >= 12.8 MB)
    size_t used4 = (size_t)(4 * m + 2) + 2048 + 5 * (size_t)n + 1;
    size_t offP  = (used4 * 4 + 255) & ~(size_t)255;
    unsigned* pairs  = (unsigned*)((char*)d_ws + offP);
    __half* scaled_a = (__half*)((char*)d_ws + offP);          // n*D halves
    __half* scaled_b = scaled_a + (size_t)n * D;               // n*D halves (keeps 256B align)
    size_t szP = 2 * (size_t)n * D * sizeof(__half);           // 25.6 MB (covers pairs 12.8 MB)
    // region Q (256B-aligned): skeys (E u8), later aliased by csr (E u32)
    size_t offQ = (offP + szP + 255) & ~(size_t)255;
    unsigned char* skeys = (unsigned char*)d_ws + offQ;
    int* csr = (int*)((char*)d_ws + offQ);

    int eblocks = nblk;
    // 1. coarse histograms (per-wave sub-hist, no global atomics)
    hist_kernel<<<eblocks, 256, 0, stream>>>(src, dst, hist_d, hist_s, nbuck, nblk, E);
    // 2. hierarchical exclusive scan of both [bucket][block] matrices
    bucket_total_kernel<<<nbuck, 256, 0, stream>>>(hist_d, hist_s, tot_d, tot_s, nblk);
    base_scan_kernel<<<1, 512, 0, stream>>>(tot_d, tot_s, base_d, base_s, nbuck);
    row_scan_kernel<<<nbuck, 512, 0, stream>>>(hist_d, hist_s, base_d, base_s,
                                               sbase_d, sbase_s, nblk, E, m);
    // 3. scatter with LDS binning: coalesced dump into bucket-grouped arrays
    scatter_kernel<<<eblocks, 256, 0, stream>>>(src, dst, sbase_d, sbase_s, pairs, skeys,
                                                nbuck, nblk, E);
    // 4. fused build: sn, dn, rowptr, csr (csr aliases skeys; pairs consumed here)
    build_kernel<<<nbuck, 256, 0, stream>>>(pairs, sbase_d, skeys, sbase_s,
                                            rowptr, csr, dn, sn, nbuck, nblk, n, E);

    // 5. propagation: prescale + 3 fused iterations (f16 ping-pong aliases pairs)
    int pblocks = (n + 3) / 4;              // prescale: wave per row
    prescale_kernel<<<pblocks, 256, 0, stream>>>(feat, sn, scaled_a, pn_a, n);
    int iblocks = ((n + 1) / 2 + 3) / 4;    // iter: 2 rows/wave, 4 waves/block
    iter_kernel<0><<<iblocks, 256, 0, stream>>>(scaled_a, feat, rowptr, csr, pn_a, dn, sn,
                                                scaled_b, pn_b, nullptr, n);
    iter_kernel<0><<<iblocks, 256, 0, stream>>>(scaled_b, feat, rowptr, csr, pn_b, dn, sn,
                                                scaled_a, pn_a, nullptr, n);
    iter_kernel<1><<<iblocks, 256, 0, stream>>>(scaled_a, feat, rowptr, csr, pn_a, dn, sn,
                                                nullptr, nullptr, out, n);
}